// Round 9
// baseline (205.217 us; speedup 1.0000x reference)
//
#include <hip/hip_runtime.h>
#include <stdint.h>

typedef short v8s __attribute__((ext_vector_type(8)));
typedef short v4s __attribute__((ext_vector_type(4)));
typedef float v4f __attribute__((ext_vector_type(4)));

#define AS1 __attribute__((address_space(1)))
#define AS3 __attribute__((address_space(3)))

__device__ __forceinline__ void glds16(const void* g, void* l) {
  __builtin_amdgcn_global_load_lds((const AS1 void*)g, (AS3 void*)l, 16, 0, 0);
}

__device__ __forceinline__ short f2bf(float f) {
  uint32_t u = __float_as_uint(f);
  u += 0x7fffu + ((u >> 16) & 1u);   // RNE; inputs are finite
  return (short)(u >> 16);
}

// ---------------- prep kernels ----------------

__global__ __launch_bounds__(256) void cast3_f32_bf16(
    const float* __restrict__ a, const float* __restrict__ b, const float* __restrict__ c,
    short* __restrict__ oa, short* __restrict__ ob, short* __restrict__ oc, int n4) {
  const float* in = (blockIdx.z == 0) ? a : (blockIdx.z == 1) ? b : c;
  short* out      = (blockIdx.z == 0) ? oa : (blockIdx.z == 1) ? ob : oc;
  int i = blockIdx.x * 256 + threadIdx.x;
  if (i < n4) {
    float4 v = ((const float4*)in)[i];
    short4 o = { f2bf(v.x), f2bf(v.y), f2bf(v.z), f2bf(v.w) };
    ((short4*)out)[i] = o;
  }
}

// All weight transposes in one dispatch. grid (16,16,4)
__global__ __launch_bounds__(256) void transpose_w_all(
    const float* __restrict__ wq, const float* __restrict__ wk, const float* __restrict__ wv,
    const float* __restrict__ wo,
    short* __restrict__ oq, short* __restrict__ ok, short* __restrict__ ov,
    short* __restrict__ oo) {
  __shared__ float tile[64][65];
  const int z = blockIdx.z;
  const float* in;
  short* out;
  int C, R, rb, cb;
  if (z < 3) {
    const int slice = blockIdx.y;
    in  = ((z == 0) ? wq : (z == 1) ? wk : wv) + (size_t)slice * 65536;
    out = ((z == 0) ? oq : (z == 1) ? ok : ov) + (size_t)slice * 65536;
    C = 64; R = 1024; rb = blockIdx.x * 64; cb = 0;
  } else {
    in = wo; out = oo;
    C = 1024; R = 1024; rb = blockIdx.x * 64; cb = blockIdx.y * 64;
  }
  int t = threadIdx.x;
  int col = t & 63, r0 = t >> 6;
#pragma unroll
  for (int i = 0; i < 16; ++i) {
    int row = r0 + i * 4;
    tile[row][col] = in[(size_t)(rb + row) * C + cb + col];
  }
  __syncthreads();
#pragma unroll
  for (int i = 0; i < 16; ++i) {
    int orow = r0 + i * 4;
    out[(size_t)(cb + orow) * R + rb + col] = f2bf(tile[col][orow]);
  }
}

// ---------------- MRx128 GEMM core — async 3-buffer pipeline + XOR bank swizzle ----
// LDS[row][p'] holds global[row][p' ^ swz(row)], swz(r) = (r&3)^((r>>2)&3).
// Store side: permute the GLOBAL part per staging lane (glds dst is lane-fixed).
// Read side: part' = quad ^ swz(c15) -> per-quad lanes spread over all 4 part slots,
// 2 lanes/bank = free (m136). Raw s_barrier + vmcnt(G): prefetch stays in flight.
template <int MR>
__device__ __forceinline__ void gemm_core(const short* __restrict__ Ag,
                                          const short* __restrict__ Bg,
                                          short* As, short* Bs,
                                          v4f (&acc)[MR / 32][4]) {
  constexpr int MT = MR / 32;
  constexpr int ASZ = MR * 32;     // shorts per A buffer
  constexpr int BSZ = 128 * 32;    // shorts per B buffer
  const int tid  = threadIdx.x;
  const int lane = tid & 63;
  const int w    = tid >> 6;
  const int quad = lane >> 4;
  const int c15  = lane & 15;
  const int wr   = (w >> 1) * (MR / 2);
  const int wc   = (w & 1) * 64;

  // staging: chunk c=tid -> row=c>>2, LDS part p'=c&3; global part = p' ^ swz(row)
  const int r0 = tid >> 2;
  const int p0 = (tid & 3) ^ ((r0 & 3) ^ ((r0 >> 2) & 3));
  const short* a0 = Ag + (size_t)r0 * 1024 + p0 * 8;
  const short* a1 = a0 + 64 * 1024;               // swz(row+64)==swz(row)
  const short* b0 = Bg + (size_t)r0 * 1024 + p0 * 8;
  const short* b1 = b0 + 64 * 1024;
  short* lA = As + tid * 8;
  short* lB = Bs + tid * 8;

  auto issue = [&](int t, int buf) {
    const int o = t * 32;
    glds16(a0 + o, lA + buf * ASZ);
    if constexpr (MR == 128) glds16(a1 + o, lA + buf * ASZ + 2048);
    glds16(b0 + o, lB + buf * BSZ);
    glds16(b1 + o, lB + buf * BSZ + 2048);
  };

  issue(0, 0);
  issue(1, 1);

  // read-side swizzled part (shorts offset = part'*8)
  const int xs = (c15 & 3) ^ ((c15 >> 2) & 3);
  const int rdoff = ((quad ^ xs)) * 8;

  for (int kb = 0; kb < 32; ++kb) {
    if constexpr (MR == 128)
      asm volatile("s_waitcnt vmcnt(4)\n\ts_barrier" ::: "memory");
    else
      asm volatile("s_waitcnt vmcnt(3)\n\ts_barrier" ::: "memory");

    const int t2 = kb + 2;
    issue(t2 < 32 ? t2 : 31, t2 % 3);   // dummy re-issue keeps vmcnt accounting uniform

    const short* Ab = As + (kb % 3) * ASZ;
    const short* Bb = Bs + (kb % 3) * BSZ;

    v8s a[MT], b[4];
#pragma unroll
    for (int mt = 0; mt < MT; ++mt)
      a[mt] = *(const v8s*)(Ab + (wr + mt * 16 + c15) * 32 + rdoff);
#pragma unroll
    for (int nt = 0; nt < 4; ++nt)
      b[nt] = *(const v8s*)(Bb + (wc + nt * 16 + c15) * 32 + rdoff);
#pragma unroll
    for (int mt = 0; mt < MT; ++mt)
#pragma unroll
      for (int nt = 0; nt < 4; ++nt)
        acc[mt][nt] = __builtin_amdgcn_mfma_f32_16x16x32_bf16(a[mt], b[nt], acc[mt][nt], 0, 0, 0);
  }
}

// ---------------- QKV projection (128x128 tiles, XCD-patch swizzle) ----------------
__global__ __launch_bounds__(256, 3) void proj_gemm(
    const short* __restrict__ xQ, const short* __restrict__ xK, const short* __restrict__ xV,
    const short* __restrict__ WqT, const short* __restrict__ WkT, const short* __restrict__ WvT,
    const float* __restrict__ bq, const float* __restrict__ bk, const float* __restrict__ bv,
    short* __restrict__ Qb, short* __restrict__ Kb, short* __restrict__ Vtb) {
  __shared__ short As[12288];   // 3 x 8 KB
  __shared__ short Bs[12288];
  const int lin = blockIdx.x;
  const int z = lin >> 8;
  const int r = lin & 255;
  const int nb = ((r >> 3) & 7) * 128;
  const int mb = (((r & 7) << 2) + (r >> 6)) * 128;
  const short* A    = (z == 0) ? xQ  : (z == 1) ? xK  : xV;
  const short* Bt   = (z == 0) ? WqT : (z == 1) ? WkT : WvT;
  const float* bias = (z == 0) ? bq  : (z == 1) ? bk  : bv;
  short* outp       = (z == 0) ? Qb  : (z == 1) ? Kb  : Vtb;
  v4f acc[4][4] = {};
  gemm_core<128>(A + (size_t)mb * 1024, Bt + (size_t)nb * 1024, As, Bs, acc);

  const int lane = threadIdx.x & 63, w = threadIdx.x >> 6;
  const int quad = lane >> 4, c15 = lane & 15;
  const int wr = (w >> 1) * 64, wc = (w & 1) * 64;
  const bool vmode = (z == 2);
#pragma unroll
  for (int nt = 0; nt < 4; ++nt) {
    const int gn = nb + wc + nt * 16 + c15;
    const float bb = bias[gn];
    const int h = gn >> 6, e = gn & 63;
#pragma unroll
    for (int mt = 0; mt < 4; ++mt) {
      if (!vmode) {
#pragma unroll
        for (int rr = 0; rr < 4; ++rr) {
          const int gm = mb + wr + mt * 16 + quad * 4 + rr;
          const int bi = gm >> 10, s = gm & 1023;
          const size_t base = (size_t)(bi * 16 + h) * 65536;
          outp[base + (size_t)s * 64 + e] = f2bf(acc[mt][nt][rr] + bb);
        }
      } else {
        const int gm0 = mb + wr + mt * 16 + quad * 4;
        const int bi = gm0 >> 10, s0 = gm0 & 1023;
        const size_t base = (size_t)(bi * 16 + h) * 65536;
        short4 st = { f2bf(acc[mt][nt][0] + bb), f2bf(acc[mt][nt][1] + bb),
                      f2bf(acc[mt][nt][2] + bb), f2bf(acc[mt][nt][3] + bb) };
        *(short4*)&outp[base + (size_t)e * 1024 + s0] = st;
      }
    }
  }
}

// ---------------- output projection (64x128 tiles, XCD-patch swizzle) ----------------
__global__ __launch_bounds__(256, 3) void out_gemm(
    const short* __restrict__ AV, const short* __restrict__ WoT,
    const float* __restrict__ bo, float* __restrict__ outp) {
  __shared__ short As[6144];    // 3 x 4 KB
  __shared__ short Bs[12288];
  const int lin = blockIdx.x;
  const int nb = ((lin >> 3) & 7) * 128;
  const int mb = (((lin & 7) << 3) + (lin >> 6)) * 64;
  v4f acc[2][4] = {};
  gemm_core<64>(AV + (size_t)mb * 1024, WoT + (size_t)nb * 1024, As, Bs, acc);
  const int lane = threadIdx.x & 63, w = threadIdx.x >> 6;
  const int quad = lane >> 4, c15 = lane & 15;
  const int wr = (w >> 1) * 32, wc = (w & 1) * 64;
#pragma unroll
  for (int nt = 0; nt < 4; ++nt) {
    const int gn = nb + wc + nt * 16 + c15;
    const float bb = bo[gn];
#pragma unroll
    for (int mt = 0; mt < 2; ++mt)
#pragma unroll
      for (int r = 0; r < 4; ++r) {
        const int gm = mb + wr + mt * 16 + quad * 4 + r;
        outp[(size_t)gm * 1024 + gn] = acc[mt][nt][r] + bb;
      }
  }
}

// ---------------- flash attention: 8 waves x 16 q-rows (2x latency hiding) --------
// Same LDS staging/swizzle and register-softmax as round 5, but 512-thread blocks:
// 16 waves/CU instead of 8, sharing the same K/V tiles (no extra L2 traffic).
__global__ __launch_bounds__(512, 4) void attn_kernel(
    const short* __restrict__ Qb, const short* __restrict__ Kb,
    const short* __restrict__ Vtb, const int* __restrict__ lens,
    short* __restrict__ AVb) {
  __shared__ short Ks[2][4096];
  __shared__ short Vs[2][4096];
  const int tid = threadIdx.x, lane = tid & 63, w = tid >> 6;   // w 0..7
  const int quad = lane >> 4, c15 = lane & 15;
  const int flat = blockIdx.x;
  const int bh = (flat & 7) + 8 * ((flat >> 3) & 7);   // XCD-L2 locality swizzle
  const int qg = flat >> 6;
  const int b = bh >> 4, h = bh & 15;
  const short* Qp = Qb  + (size_t)bh * 65536;
  const short* Kp = Kb  + (size_t)bh * 65536;
  const short* Vp = Vtb + (size_t)bh * 65536;
  const int len = lens[b];
  const int row0 = qg * 128 + w * 16;    // this wave's 16 q-rows

  // Q as B-operand frags: B[n=query=c15][k=dh=kf*32+quad*8+j]
  v8s bq_[2];
#pragma unroll
  for (int kf = 0; kf < 2; ++kf)
    bq_[kf] = *(const v8s*)(Qp + (size_t)(row0 + c15) * 64 + kf * 32 + quad * 8);

  const float scale = (row0 + c15 < len) ? 0.125f : 0.0f;
  float sm = 0.f;
  v4f o[4] = {};             // O^T: row=dh=t*16+quad*4+r, col=query=c15

  // staging: 512 chunks of 16B = one K tile (or V tile); chunk c=tid:
  // row=tid>>3, LDS part=tid&7, global part = part ^ (row&7)
  const int srow = tid >> 3, spart = tid & 7;
  const int gpart = spart ^ (srow & 7);
  const int kgo = srow * 64 + gpart * 8;
  const int vgo = srow * 1024 + gpart * 8;
  const int l0 = tid * 8;

  const int c7 = c15 & 7;
  const int krow = c15 * 128;
  const int koff0 = krow + ((quad) ^ c7) * 16;
  const int koff1 = krow + ((4 + quad) ^ c7) * 16;
  const int q2 = quad >> 1, h8 = (quad & 1) * 8;
  int voff[4];
#pragma unroll
  for (int nt = 0; nt < 4; ++nt)
    voff[nt] = krow + ((2 * nt + q2) ^ c7) * 16 + h8;

  glds16(Kp + kgo, (char*)Ks[0] + l0 * 2);
  glds16(Vp + vgo, (char*)Vs[0] + l0 * 2);

  for (int kb = 0; kb < 16; ++kb) {
    const int cur = kb & 1, nxt = cur ^ 1;
    __syncthreads();

    if (kb < 15) {
      glds16(Kp + (size_t)(kb + 1) * 4096 + kgo, (char*)Ks[nxt] + l0 * 2);
      glds16(Vp + (kb + 1) * 64 + vgo, (char*)Vs[nxt] + l0 * 2);
    }

    // K A-frags from LDS: A[m=key=c15][k=dh]
    v8s ak[4][2];
#pragma unroll
    for (int nt = 0; nt < 4; ++nt) {
      ak[nt][0] = *(const v8s*)((const char*)Ks[cur] + nt * 2048 + koff0);
      ak[nt][1] = *(const v8s*)((const char*)Ks[cur] + nt * 2048 + koff1);
    }

    // S^T = K Q^T
    v4f sc[4];
#pragma unroll
    for (int nt = 0; nt < 4; ++nt) {
      v4f z = {};
#pragma unroll
      for (int kf = 0; kf < 2; ++kf)
        z = __builtin_amdgcn_mfma_f32_16x16x32_bf16(ak[nt][kf], bq_[kf], z, 0, 0, 0);
      sc[nt] = z;
    }

    // softmax numerator in-register (per-query scale/mask on col lane c15)
    v4s pb[4];
#pragma unroll
    for (int nt = 0; nt < 4; ++nt) {
      v4s pv;
#pragma unroll
      for (int r = 0; r < 4; ++r) {
        float p = __expf(sc[nt][r] * scale);
        sm += p;
        pv[r] = f2bf(p);
      }
      pb[nt] = pv;
    }

    // V^T A-frags (x16): A[m=dh=t*16+c15][k=key=nt*16+quad*4+j] — after exp so
    // ak registers die before av live (VGPR headroom for 4 waves/EU)
    v4s av[4][4];
#pragma unroll
    for (int t = 0; t < 4; ++t)
#pragma unroll
      for (int nt = 0; nt < 4; ++nt)
        av[t][nt] = *(const v4s*)((const char*)Vs[cur] + t * 2048 + voff[nt]);

    // O^T += V^T P^T
#pragma unroll
    for (int t = 0; t < 4; ++t)
#pragma unroll
      for (int nt = 0; nt < 4; ++nt)
        o[t] = __builtin_amdgcn_mfma_f32_16x16x16bf16_1k(av[t][nt], pb[nt], o[t], 0, 0, 0);
  }

  // denominator: keys spread over quads only (r, nt summed in-lane)
  sm += __shfl_xor(sm, 16);
  sm += __shfl_xor(sm, 32);

  const float inv = 1.0f / sm;
  const size_t rowbase = (size_t)(b * 1024 + row0 + c15) * 1024 + h * 64;
#pragma unroll
  for (int t = 0; t < 4; ++t) {
    short4 st = { f2bf(o[t][0] * inv), f2bf(o[t][1] * inv),
                  f2bf(o[t][2] * inv), f2bf(o[t][3] * inv) };
    *(short4*)&AVb[rowbase + t * 16 + quad * 4] = st;
  }
}

// ---------------- launch ----------------
extern "C" void kernel_launch(void* const* d_in, const int* in_sizes, int n_in,
                              void* d_out, int out_size, void* d_ws, size_t ws_size,
                              hipStream_t stream) {
  const float* xQ = (const float*)d_in[0];
  const float* xK = (const float*)d_in[1];
  const float* xV = (const float*)d_in[2];
  const int* lens = (const int*)d_in[3];
  const float* Wq = (const float*)d_in[4];
  const float* bq = (const float*)d_in[5];
  const float* Wk = (const float*)d_in[6];
  const float* bk = (const float*)d_in[7];
  const float* Wv = (const float*)d_in[8];
  const float* bv = (const float*)d_in[9];
  const float* Wo = (const float*)d_in[10];
  const float* bo = (const float*)d_in[11];
  float* out = (float*)d_out;

  char* ws = (char*)d_ws;
  short* xQb = (short*)(ws + 0);                 // 8 MB  [4096][1024] bf16
  short* xKb = (short*)(ws + 8388608);
  short* xVb = (short*)(ws + 16777216);
  short* WqT = (short*)(ws + 25165824);          // 2 MB  [n=h*64+e][d]
  short* WkT = (short*)(ws + 27262976);
  short* WvT = (short*)(ws + 29360128);
  short* WoT = (short*)(ws + 31457280);          // 2 MB  Wo^T [n][k]
  short* Qb  = (short*)(ws + 33554432);          // 8 MB  [b,h,s,e]
  short* Kb  = (short*)(ws + 41943040);          // 8 MB  [b,h,s,e]
  short* Vtb = (short*)(ws + 50331648);          // 8 MB  [b,h,e,s]
  short* AVb = (short*)(ws + 58720256);          // 8 MB  [b,s,h*64+e]

  cast3_f32_bf16<<<dim3(4096, 1, 3), 256, 0, stream>>>(xQ, xK, xV, xQb, xKb, xVb, 1048576);
  transpose_w_all<<<dim3(16, 16, 4), 256, 0, stream>>>(Wq, Wk, Wv, Wo, WqT, WkT, WvT, WoT);
  proj_gemm<<<dim3(768), 256, 0, stream>>>(xQb, xKb, xVb, WqT, WkT, WvT,
                                           bq, bk, bv, Qb, Kb, Vtb);
  attn_kernel<<<dim3(512), 512, 0, stream>>>(Qb, Kb, Vtb, lens, AVb);
  out_gemm<<<dim3(512), 256, 0, stream>>>(AVb, WoT, bo, out);
}

// Round 10
// 203.050 us; speedup vs baseline: 1.0107x; 1.0107x over previous
//
#include <hip/hip_runtime.h>
#include <stdint.h>

typedef short v8s __attribute__((ext_vector_type(8)));
typedef short v4s __attribute__((ext_vector_type(4)));
typedef float v4f __attribute__((ext_vector_type(4)));

#define AS1 __attribute__((address_space(1)))
#define AS3 __attribute__((address_space(3)))

__device__ __forceinline__ void glds16(const void* g, void* l) {
  __builtin_amdgcn_global_load_lds((const AS1 void*)g, (AS3 void*)l, 16, 0, 0);
}

__device__ __forceinline__ short f2bf(float f) {
  uint32_t u = __float_as_uint(f);
  u += 0x7fffu + ((u >> 16) & 1u);   // RNE; inputs are finite
  return (short)(u >> 16);
}

// ---------------- fused prep: input casts + all weight transposes ----------------
// flat grid 13312: blocks [0,768) per-head W transpose, [768,1024) Wo transpose,
// [1024,13312) fp32->bf16 casts. Transpose blocks dispatch first (latency-bound),
// cast blocks (HBM-bound) stream behind and overlap them.
__global__ __launch_bounds__(256) void prep_kernel(
    const float* __restrict__ xQ, const float* __restrict__ xK, const float* __restrict__ xV,
    const float* __restrict__ wq, const float* __restrict__ wk, const float* __restrict__ wv,
    const float* __restrict__ wo,
    short* __restrict__ oxQ, short* __restrict__ oxK, short* __restrict__ oxV,
    short* __restrict__ oq, short* __restrict__ ok, short* __restrict__ ov,
    short* __restrict__ oo) {
  const int bid = blockIdx.x;
  const int t = threadIdx.x;
  if (bid >= 1024) {
    const int c = bid - 1024;
    const int z = c >> 12;
    const int i = (c & 4095) * 256 + t;
    const float* in = (z == 0) ? xQ : (z == 1) ? xK : xV;
    short* out      = (z == 0) ? oxQ : (z == 1) ? oxK : oxV;
    float4 v = ((const float4*)in)[i];
    short4 o = { f2bf(v.x), f2bf(v.y), f2bf(v.z), f2bf(v.w) };
    ((short4*)out)[i] = o;
    return;
  }
  __shared__ float tile[64][65];
  const float* in;
  short* out;
  int C, R, rb, cb;
  if (bid < 768) {
    const int which = bid >> 8, rem = bid & 255;
    const int slice = rem >> 4, rbi = rem & 15;
    in  = ((which == 0) ? wq : (which == 1) ? wk : wv) + (size_t)slice * 65536;
    out = ((which == 0) ? oq : (which == 1) ? ok : ov) + (size_t)slice * 65536;
    C = 64; R = 1024; rb = rbi * 64; cb = 0;
  } else {
    const int r = bid - 768;
    in = wo; out = oo;
    C = 1024; R = 1024; rb = (r >> 4) * 64; cb = (r & 15) * 64;
  }
  const int col = t & 63, r0 = t >> 6;
#pragma unroll
  for (int i = 0; i < 16; ++i) {
    int row = r0 + i * 4;
    tile[row][col] = in[(size_t)(rb + row) * C + cb + col];
  }
  __syncthreads();
#pragma unroll
  for (int i = 0; i < 16; ++i) {
    int orow = r0 + i * 4;
    out[(size_t)(cb + orow) * R + rb + col] = f2bf(tile[col][orow]);
  }
}

// ---------------- MRx128 GEMM core — async 3-buffer pipeline + XOR bank swizzle ----
// NOTE: SQ_LDS_BANK_CONFLICT has a fixed floor of 8 per glds16 (DMA 1KB write =
// 8 LDS cycles) — 3.1M for proj is that artifact, not real read conflicts.
template <int MR>
__device__ __forceinline__ void gemm_core(const short* __restrict__ Ag,
                                          const short* __restrict__ Bg,
                                          short* As, short* Bs,
                                          v4f (&acc)[MR / 32][4]) {
  constexpr int MT = MR / 32;
  constexpr int ASZ = MR * 32;     // shorts per A buffer
  constexpr int BSZ = 128 * 32;    // shorts per B buffer
  const int tid  = threadIdx.x;
  const int lane = tid & 63;
  const int w    = tid >> 6;
  const int quad = lane >> 4;
  const int c15  = lane & 15;
  const int wr   = (w >> 1) * (MR / 2);
  const int wc   = (w & 1) * 64;

  const int r0 = tid >> 2;
  const int p0 = (tid & 3) ^ ((r0 & 3) ^ ((r0 >> 2) & 3));
  const short* a0 = Ag + (size_t)r0 * 1024 + p0 * 8;
  const short* a1 = a0 + 64 * 1024;
  const short* b0 = Bg + (size_t)r0 * 1024 + p0 * 8;
  const short* b1 = b0 + 64 * 1024;
  short* lA = As + tid * 8;
  short* lB = Bs + tid * 8;

  auto issue = [&](int t, int buf) {
    const int o = t * 32;
    glds16(a0 + o, lA + buf * ASZ);
    if constexpr (MR == 128) glds16(a1 + o, lA + buf * ASZ + 2048);
    glds16(b0 + o, lB + buf * BSZ);
    glds16(b1 + o, lB + buf * BSZ + 2048);
  };

  issue(0, 0);
  issue(1, 1);

  const int xs = (c15 & 3) ^ ((c15 >> 2) & 3);
  const int rdoff = ((quad ^ xs)) * 8;

  for (int kb = 0; kb < 32; ++kb) {
    if constexpr (MR == 128)
      asm volatile("s_waitcnt vmcnt(4)\n\ts_barrier" ::: "memory");
    else
      asm volatile("s_waitcnt vmcnt(3)\n\ts_barrier" ::: "memory");

    const int t2 = kb + 2;
    issue(t2 < 32 ? t2 : 31, t2 % 3);

    const short* Ab = As + (kb % 3) * ASZ;
    const short* Bb = Bs + (kb % 3) * BSZ;

    v8s a[MT], b[4];
#pragma unroll
    for (int mt = 0; mt < MT; ++mt)
      a[mt] = *(const v8s*)(Ab + (wr + mt * 16 + c15) * 32 + rdoff);
#pragma unroll
    for (int nt = 0; nt < 4; ++nt)
      b[nt] = *(const v8s*)(Bb + (wc + nt * 16 + c15) * 32 + rdoff);
#pragma unroll
    for (int mt = 0; mt < MT; ++mt)
#pragma unroll
      for (int nt = 0; nt < 4; ++nt)
        acc[mt][nt] = __builtin_amdgcn_mfma_f32_16x16x32_bf16(a[mt], b[nt], acc[mt][nt], 0, 0, 0);
  }
}

// ---------------- QKV projection (128x128 tiles, XCD-patch swizzle) ----------------
__global__ __launch_bounds__(256, 3) void proj_gemm(
    const short* __restrict__ xQ, const short* __restrict__ xK, const short* __restrict__ xV,
    const short* __restrict__ WqT, const short* __restrict__ WkT, const short* __restrict__ WvT,
    const float* __restrict__ bq, const float* __restrict__ bk, const float* __restrict__ bv,
    short* __restrict__ Qb, short* __restrict__ Kb, short* __restrict__ Vtb) {
  __shared__ short As[12288];
  __shared__ short Bs[12288];
  const int lin = blockIdx.x;
  const int z = lin >> 8;
  const int r = lin & 255;
  const int nb = ((r >> 3) & 7) * 128;
  const int mb = (((r & 7) << 2) + (r >> 6)) * 128;
  const short* A    = (z == 0) ? xQ  : (z == 1) ? xK  : xV;
  const short* Bt   = (z == 0) ? WqT : (z == 1) ? WkT : WvT;
  const float* bias = (z == 0) ? bq  : (z == 1) ? bk  : bv;
  short* outp       = (z == 0) ? Qb  : (z == 1) ? Kb  : Vtb;
  v4f acc[4][4] = {};
  gemm_core<128>(A + (size_t)mb * 1024, Bt + (size_t)nb * 1024, As, Bs, acc);

  const int lane = threadIdx.x & 63, w = threadIdx.x >> 6;
  const int quad = lane >> 4, c15 = lane & 15;
  const int wr = (w >> 1) * 64, wc = (w & 1) * 64;
  const bool vmode = (z == 2);
#pragma unroll
  for (int nt = 0; nt < 4; ++nt) {
    const int gn = nb + wc + nt * 16 + c15;
    const float bb = bias[gn];
    const int h = gn >> 6, e = gn & 63;
#pragma unroll
    for (int mt = 0; mt < 4; ++mt) {
      if (!vmode) {
#pragma unroll
        for (int rr = 0; rr < 4; ++rr) {
          const int gm = mb + wr + mt * 16 + quad * 4 + rr;
          const int bi = gm >> 10, s = gm & 1023;
          const size_t base = (size_t)(bi * 16 + h) * 65536;
          outp[base + (size_t)s * 64 + e] = f2bf(acc[mt][nt][rr] + bb);
        }
      } else {
        const int gm0 = mb + wr + mt * 16 + quad * 4;
        const int bi = gm0 >> 10, s0 = gm0 & 1023;
        const size_t base = (size_t)(bi * 16 + h) * 65536;
        short4 st = { f2bf(acc[mt][nt][0] + bb), f2bf(acc[mt][nt][1] + bb),
                      f2bf(acc[mt][nt][2] + bb), f2bf(acc[mt][nt][3] + bb) };
        *(short4*)&outp[base + (size_t)e * 1024 + s0] = st;
      }
    }
  }
}

// ---------------- output projection (64x128 tiles, XCD-patch swizzle) ----------------
__global__ __launch_bounds__(256, 3) void out_gemm(
    const short* __restrict__ AV, const short* __restrict__ WoT,
    const float* __restrict__ bo, float* __restrict__ outp) {
  __shared__ short As[6144];
  __shared__ short Bs[12288];
  const int lin = blockIdx.x;
  const int nb = ((lin >> 3) & 7) * 128;
  const int mb = (((lin & 7) << 3) + (lin >> 6)) * 64;
  v4f acc[2][4] = {};
  gemm_core<64>(AV + (size_t)mb * 1024, WoT + (size_t)nb * 1024, As, Bs, acc);
  const int lane = threadIdx.x & 63, w = threadIdx.x >> 6;
  const int quad = lane >> 4, c15 = lane & 15;
  const int wr = (w >> 1) * 32, wc = (w & 1) * 64;
#pragma unroll
  for (int nt = 0; nt < 4; ++nt) {
    const int gn = nb + wc + nt * 16 + c15;
    const float bb = bo[gn];
#pragma unroll
    for (int mt = 0; mt < 2; ++mt)
#pragma unroll
      for (int r = 0; r < 4; ++r) {
        const int gm = mb + wr + mt * 16 + quad * 4 + r;
        outp[(size_t)gm * 1024 + gn] = acc[mt][nt][r] + bb;
      }
  }
}

// ---------------- flash attention: grid 1024 (4 blocks/CU), 4 waves x 16 q-rows ----
// Finer q-split doubles resident blocks/CU 2->4 so cross-block overlap (m114)
// covers each block's __syncthreads vmcnt(0) drain. K/V tiles L2-resident per XCD.
__global__ __launch_bounds__(256, 4) void attn_kernel(
    const short* __restrict__ Qb, const short* __restrict__ Kb,
    const short* __restrict__ Vtb, const int* __restrict__ lens,
    short* __restrict__ AVb) {
  __shared__ short Ks[2][4096];
  __shared__ short Vs[2][4096];
  const int tid = threadIdx.x, lane = tid & 63, w = tid >> 6;   // w 0..3
  const int quad = lane >> 4, c15 = lane & 15;
  const int flat = blockIdx.x;
  const int bh = (flat & 7) + 8 * ((flat >> 3) & 7);   // all 16 q-blocks of bh on one XCD
  const int qg = flat >> 6;                            // 0..15, 64 q-rows each
  const int b = bh >> 4, h = bh & 15;
  const short* Qp = Qb  + (size_t)bh * 65536;
  const short* Kp = Kb  + (size_t)bh * 65536;
  const short* Vp = Vtb + (size_t)bh * 65536;
  const int len = lens[b];
  const int row0 = qg * 64 + w * 16;    // this wave's 16 q-rows

  // Q as B-operand frags: B[n=query=c15][k=dh=kf*32+quad*8+j]
  v8s bq_[2];
#pragma unroll
  for (int kf = 0; kf < 2; ++kf)
    bq_[kf] = *(const v8s*)(Qp + (size_t)(row0 + c15) * 64 + kf * 32 + quad * 8);

  const float scale = (row0 + c15 < len) ? 0.125f : 0.0f;
  float sm = 0.f;
  v4f o[4] = {};             // O^T: row=dh=t*16+quad*4+r, col=query=c15

  // staging: K/V tiles 8KB each; 256 threads x 2 chunks of 16B.
  // row=chunk>>3, LDS part=chunk&7, global part = part ^ (row&7)
  const int srow = tid >> 3, spart = tid & 7;
  const int gpart = spart ^ (srow & 7);
  const int kgo0 = srow * 64 + gpart * 8, kgo1 = (srow + 32) * 64 + gpart * 8;
  const int vgo0 = srow * 1024 + gpart * 8, vgo1 = (srow + 32) * 1024 + gpart * 8;
  const int l0 = tid * 8, l1 = 2048 + tid * 8;

  const int c7 = c15 & 7;
  const int krow = c15 * 128;
  const int koff0 = krow + ((quad) ^ c7) * 16;
  const int koff1 = krow + ((4 + quad) ^ c7) * 16;
  const int q2 = quad >> 1, h8 = (quad & 1) * 8;
  int voff[4];
#pragma unroll
  for (int nt = 0; nt < 4; ++nt)
    voff[nt] = krow + ((2 * nt + q2) ^ c7) * 16 + h8;

  glds16(Kp + kgo0, (char*)Ks[0] + l0 * 2);
  glds16(Kp + kgo1, (char*)Ks[0] + l1 * 2);
  glds16(Vp + vgo0, (char*)Vs[0] + l0 * 2);
  glds16(Vp + vgo1, (char*)Vs[0] + l1 * 2);

  for (int kb = 0; kb < 16; ++kb) {
    const int cur = kb & 1, nxt = cur ^ 1;
    __syncthreads();

    if (kb < 15) {
      const short* kt = Kp + (size_t)(kb + 1) * 4096;
      const short* vt = Vp + (kb + 1) * 64;
      glds16(kt + kgo0, (char*)Ks[nxt] + l0 * 2);
      glds16(kt + kgo1, (char*)Ks[nxt] + l1 * 2);
      glds16(vt + vgo0, (char*)Vs[nxt] + l0 * 2);
      glds16(vt + vgo1, (char*)Vs[nxt] + l1 * 2);
    }

    // K A-frags from LDS: A[m=key=c15][k=dh]
    v8s ak[4][2];
#pragma unroll
    for (int nt = 0; nt < 4; ++nt) {
      ak[nt][0] = *(const v8s*)((const char*)Ks[cur] + nt * 2048 + koff0);
      ak[nt][1] = *(const v8s*)((const char*)Ks[cur] + nt * 2048 + koff1);
    }

    // S^T = K Q^T
    v4f sc[4];
#pragma unroll
    for (int nt = 0; nt < 4; ++nt) {
      v4f z = {};
#pragma unroll
      for (int kf = 0; kf < 2; ++kf)
        z = __builtin_amdgcn_mfma_f32_16x16x32_bf16(ak[nt][kf], bq_[kf], z, 0, 0, 0);
      sc[nt] = z;
    }

    // softmax numerator in-register
    v4s pb[4];
#pragma unroll
    for (int nt = 0; nt < 4; ++nt) {
      v4s pv;
#pragma unroll
      for (int r = 0; r < 4; ++r) {
        float p = __expf(sc[nt][r] * scale);
        sm += p;
        pv[r] = f2bf(p);
      }
      pb[nt] = pv;
    }

    // V^T A-frags after exp (ak dead -> av live: VGPR headroom)
    v4s av[4][4];
#pragma unroll
    for (int t = 0; t < 4; ++t)
#pragma unroll
      for (int nt = 0; nt < 4; ++nt)
        av[t][nt] = *(const v4s*)((const char*)Vs[cur] + t * 2048 + voff[nt]);

    // O^T += V^T P^T
#pragma unroll
    for (int t = 0; t < 4; ++t)
#pragma unroll
      for (int nt = 0; nt < 4; ++nt)
        o[t] = __builtin_amdgcn_mfma_f32_16x16x16bf16_1k(av[t][nt], pb[nt], o[t], 0, 0, 0);
  }

  sm += __shfl_xor(sm, 16);
  sm += __shfl_xor(sm, 32);

  const float inv = 1.0f / sm;
  const size_t rowbase = (size_t)(b * 1024 + row0 + c15) * 1024 + h * 64;
#pragma unroll
  for (int t = 0; t < 4; ++t) {
    short4 st = { f2bf(o[t][0] * inv), f2bf(o[t][1] * inv),
                  f2bf(o[t][2] * inv), f2bf(o[t][3] * inv) };
    *(short4*)&AVb[rowbase + t * 16 + quad * 4] = st;
  }
}

// ---------------- launch ----------------
extern "C" void kernel_launch(void* const* d_in, const int* in_sizes, int n_in,
                              void* d_out, int out_size, void* d_ws, size_t ws_size,
                              hipStream_t stream) {
  const float* xQ = (const float*)d_in[0];
  const float* xK = (const float*)d_in[1];
  const float* xV = (const float*)d_in[2];
  const int* lens = (const int*)d_in[3];
  const float* Wq = (const float*)d_in[4];
  const float* bq = (const float*)d_in[5];
  const float* Wk = (const float*)d_in[6];
  const float* bk = (const float*)d_in[7];
  const float* Wv = (const float*)d_in[8];
  const float* bv = (const float*)d_in[9];
  const float* Wo = (const float*)d_in[10];
  const float* bo = (const float*)d_in[11];
  float* out = (float*)d_out;

  char* ws = (char*)d_ws;
  short* xQb = (short*)(ws + 0);                 // 8 MB  [4096][1024] bf16
  short* xKb = (short*)(ws + 8388608);
  short* xVb = (short*)(ws + 16777216);
  short* WqT = (short*)(ws + 25165824);          // 2 MB  [n=h*64+e][d]
  short* WkT = (short*)(ws + 27262976);
  short* WvT = (short*)(ws + 29360128);
  short* WoT = (short*)(ws + 31457280);          // 2 MB  Wo^T [n][k]
  short* Qb  = (short*)(ws + 33554432);          // 8 MB  [b,h,s,e]
  short* Kb  = (short*)(ws + 41943040);          // 8 MB  [b,h,s,e]
  short* Vtb = (short*)(ws + 50331648);          // 8 MB  [b,h,e,s]
  short* AVb = (short*)(ws + 58720256);          // 8 MB  [b,s,h*64+e]

  prep_kernel<<<dim3(13312), 256, 0, stream>>>(xQ, xK, xV, Wq, Wk, Wv, Wo,
                                               xQb, xKb, xVb, WqT, WkT, WvT, WoT);
  proj_gemm<<<dim3(768), 256, 0, stream>>>(xQb, xKb, xVb, WqT, WkT, WvT,
                                           bq, bk, bv, Qb, Kb, Vtb);
  attn_kernel<<<dim3(1024), 256, 0, stream>>>(Qb, Kb, Vtb, lens, AVb);
  out_gemm<<<dim3(512), 256, 0, stream>>>(AVb, WoT, bo, out);
}